// Round 1
// 156.073 us; speedup vs baseline: 1.3319x; 1.3319x over previous
//
#include <hip/hip_runtime.h>

// QuantizationLayer: lerp-table MLP + LDS-hist bucket sort + linked-list gather.
// R1: 18M scattered global atomics = 868 us (scattered-transaction ceiling ~21G/s).
// R4-R7: bucket sort + LDS-tile gather: three different gather structures
//   ALL land at ~110-130us -> invariant is 18M LDS f32 atomicAdds (~90 us floor).
// R8: gather rebuilt atomic-free: per-x linked lists in LDS (one atomicExch
//   per event = 2M), thread-per-column walks its list accumulating 9 bins in
//   registers, coalesced direct store. 207.9 us total.
// R9 (this round): rocprof showed build_table_kernel is the TOP dispatch
//   (59-74 us, ~1/3 of total): 9 blocks on 256 CUs (0.35% occupancy) AND
//   float acc[100] spilled to scratch (VGPR_Count=52 < 100 needed) -> every
//   inner FMA paid a scratch round-trip. Rebuilt block-per-sample: 2049 blocks
//   x 128 threads, lane k owns hidden unit k, h1 in LDS (broadcast), 100-deep
//   dependent FMA chain in a single register, LDS tree reduce. 42 MFLOP total
//   => should be launch/latency bound at a few us. Predicted total ~145 us.

#define HID 100

constexpr int Wd = 336;
constexpr int Hd = 256;
constexpr int Cd = 9;                  // C_BINS
constexpr int HW = Wd * Hd;            // 86016
constexpr int PLANE = HW * Cd;         // 774144
constexpr int BATCH = PLANE * 2;       // 1548288

constexpr int NBUCKET = 4096;          // ((b*2+p01)<<8) | y
constexpr int CAP = 1024;              // max events/bucket (mean 488, +24 sigma)
constexpr int PB_THREADS = 512;
constexpr int PB_PER_THREAD = 16;
constexpr int PB_EVENTS = PB_THREADS * PB_PER_THREAD;   // 8192 events/block
constexpr int TABLE_N = 2048;

// ---- zero the 4096 bucket cursors (no hipMemsetAsync inside capture) --
__global__ void zero_kernel(unsigned* __restrict__ p, int n) {
    int i = blockIdx.x * blockDim.x + threadIdx.x;
    if (i < n) p[i] = 0u;
}

// ---- table build: block per sample, lane per hidden unit --------------
// h2[k] = lrelu( sum_j h1[j] * w2[j][k] + b2[k] );  o = sum_k h2[k]*w3[k] + b3
// h1 lives in LDS (all-lanes-same-address reads broadcast, conflict-free);
// w2 column reads are coalesced across lanes and L2-resident (40 KB shared
// by all 2049 blocks). Dependent chain per lane: 100 FMAs (~400 cy).
__global__ __launch_bounds__(128) void
build_table_kernel(const float* __restrict__ w1,
                   const float* __restrict__ b1,
                   const float* __restrict__ w2,
                   const float* __restrict__ b2,
                   const float* __restrict__ w3,
                   const float* __restrict__ b3,
                   float* __restrict__ table, int table_n) {
    __shared__ float h1[HID];
    __shared__ float partial[128];
    int i = blockIdx.x;                 // 0 .. table_n inclusive
    if (i > table_n) return;
    int tid = threadIdx.x;
    float s = -1.0f + 2.0f * (float)i / (float)table_n;

    if (tid < HID) {
        float h = fmaf(s, w1[tid], b1[tid]);
        h1[tid] = fmaxf(h, 0.1f * h);
    }
    __syncthreads();

    float o = 0.0f;
    if (tid < HID) {
        // 4 partial accumulators break the dependent-FMA latency chain
        float a0 = b2[tid], a1 = 0.0f, a2 = 0.0f, a3 = 0.0f;
#pragma unroll
        for (int j = 0; j < HID; j += 4) {
            a0 = fmaf(h1[j + 0], w2[(j + 0) * HID + tid], a0);
            a1 = fmaf(h1[j + 1], w2[(j + 1) * HID + tid], a1);
            a2 = fmaf(h1[j + 2], w2[(j + 2) * HID + tid], a2);
            a3 = fmaf(h1[j + 3], w2[(j + 3) * HID + tid], a3);
        }
        float acc = (a0 + a1) + (a2 + a3);
        float h2 = fmaxf(acc, 0.1f * acc);
        o = h2 * w3[tid];
    }
    partial[tid] = o;
    __syncthreads();
#pragma unroll
    for (int s2 = 64; s2 > 0; s2 >>= 1) {
        if (tid < s2) partial[tid] += partial[tid + s2];
        __syncthreads();
    }
    if (tid == 0) table[i] = partial[0] + b3[0];
}

// ---- place3: LDS-hist bucket sort, single count pass ------------------
__global__ __launch_bounds__(PB_THREADS) void
place3_kernel(const float* __restrict__ ev, int n,
              unsigned* __restrict__ gCursor,
              unsigned* __restrict__ bucketData) {
    __shared__ unsigned cnt[NBUCKET];    // 16 KB
    __shared__ unsigned base[NBUCKET];   // 16 KB
    int tid = threadIdx.x;
    for (int c = tid; c < NBUCKET; c += PB_THREADS) cnt[c] = 0u;
    __syncthreads();

    int ev0 = blockIdx.x * PB_EVENTS;
    unsigned pk[PB_PER_THREAD];          // packed (x<<23)|t_q23
    unsigned meta[PB_PER_THREAD];        // (bucket<<13)|rank, or ~0 = invalid

    // phase 1: count via LDS atomic; the RETURN VALUE is the local rank
#pragma unroll
    for (int j = 0; j < PB_PER_THREAD; ++j) {
        int i = ev0 + tid + j * PB_THREADS;
        if (i < n) {
            const float* e = ev + (size_t)i * 5;
            int p01 = e[3] > 0.0f ? 1 : 0;
            unsigned bucket = (unsigned)(((p01 + 2 * (int)e[4]) << 8) | (int)e[1]);
            unsigned tq = (unsigned)(e[2] * 8388608.0f);   // t in [0,1) -> 23b
            pk[j] = ((unsigned)(int)e[0] << 23) | tq;
            unsigned r = atomicAdd(&cnt[bucket], 1u);      // local rank
            meta[j] = (bucket << 13) | r;                  // r < 8192
        } else {
            meta[j] = 0xFFFFFFFFu;
        }
    }
    __syncthreads();

    // phase 2: merge per-block counts into global cursors -> base
    for (int c = tid; c < NBUCKET; c += PB_THREADS) {
        unsigned k = cnt[c];
        base[c] = k ? atomicAdd(&gCursor[c], k) : 0u;
    }
    __syncthreads();

    // phase 3: pure stores to exact slots (no second count pass)
#pragma unroll
    for (int j = 0; j < PB_PER_THREAD; ++j) {
        unsigned m = meta[j];
        if (m != 0xFFFFFFFFu) {
            unsigned bucket = m >> 13;
            unsigned pos = base[bucket] + (m & 0x1FFFu);
            if (pos < CAP)   // statistically impossible overflow; guard OOB
                bucketData[(size_t)bucket * CAP + pos] = pk[j];
        }
    }
}

// ---- gather7: block per bucket, per-column linked lists, no atomic acc -
__global__ __launch_bounds__(256) void
gather7_kernel(const unsigned* __restrict__ gCursor,
               const unsigned* __restrict__ bucketData,
               const float* __restrict__ gtable,
               float* __restrict__ out) {
    __shared__ float table[TABLE_N + 1];   // 8.2 KB
    __shared__ int   head[Wd];             // 1.3 KB
    __shared__ int   nxt[CAP];             // 4 KB
    __shared__ unsigned evs[CAP];          // 4 KB   (total 17.5 KB -> 8 blk/CU)
    int tid = threadIdx.x;
    int bucket = blockIdx.x;
    for (int i = tid; i < TABLE_N + 1; i += 256) table[i] = gtable[i];
    for (int i = tid; i < Wd; i += 256) head[i] = -1;
    __syncthreads();

    unsigned c = gCursor[bucket];
    if (c > CAP) c = CAP;
    const unsigned* __restrict__ data = bucketData + (size_t)bucket * CAP;

    // phase 1: stash events, build per-x linked lists (1 atomicExch/event)
    for (unsigned e = tid; e < c; e += 256) {
        unsigned pkd = data[e];
        evs[e] = pkd;
        int x = (int)(pkd >> 23);
        nxt[e] = atomicExch(&head[x], (int)e);
    }
    __syncthreads();

    int y = bucket & 255;
    int bp = bucket >> 8;                 // p01 + 2*b
    int b = bp >> 1, p01 = bp & 1;
    size_t rowbase = (size_t)(b * (2 * Cd) + p01 * Cd) * (size_t)HW
                   + (size_t)y * (size_t)Wd;

    // phase 2: thread-per-column list walk, 9 register accumulators,
    // coalesced direct store (covers empty columns with zeros).
    for (int x = tid; x < Wd; x += 256) {
        float acc[Cd];
#pragma unroll
        for (int k = 0; k < Cd; ++k) acc[k] = 0.0f;
        for (int e = head[x]; e != -1; e = nxt[e]) {
            unsigned pkd = evs[e];
            float t = (float)(pkd & 0x7FFFFFu) * (1.0f / 8388608.0f);
            float u0 = (t + 1.0f) * (0.5f * (float)TABLE_N);  // in [1024,2048)
            int ii0 = (int)u0;                                 // [1024,2047]
            float fr = u0 - (float)ii0;                        // shared by all k
#pragma unroll
            for (int k = 0; k < Cd; ++k) {
                int ii = ii0 - 128 * k;        // k/8 shift = exactly 128 cells
                float t0 = table[ii], t1 = table[ii + 1];
                acc[k] = fmaf(t, fmaf(fr, t1 - t0, t0), acc[k]);
            }
        }
#pragma unroll
        for (int k = 0; k < Cd; ++k)
            out[rowbase + (size_t)k * HW + x] = acc[k];
    }
}

// ---- round-1 fallback scatter (known-good; used if ws too small) ------
__global__ void zero_out_kernel(float* __restrict__ p, int n) {
    int i = blockIdx.x * blockDim.x + threadIdx.x;
    if (i < n) p[i] = 0.0f;
}

__global__ void scatter_kernel(const float* __restrict__ ev, int n,
                               const float* __restrict__ table, int table_n,
                               float* __restrict__ out) {
    int i = blockIdx.x * blockDim.x + threadIdx.x;
    if (i >= n) return;
    const float* e = ev + (size_t)i * 5;
    float t = e[2];
    int idx0 = (int)e[0] + Wd * (int)e[1] + (e[3] > 0.0f ? PLANE : 0) + BATCH * (int)e[4];
    float half_n = 0.5f * (float)table_n;
#pragma unroll
    for (int k = 0; k < Cd; ++k) {
        float u = (t - 0.125f * (float)k + 1.0f) * half_n;
        int ii = (int)u;
        ii = ii < 0 ? 0 : (ii > table_n - 1 ? table_n - 1 : ii);
        float fr = u - (float)ii;
        float t0 = table[ii], t1 = table[ii + 1];
        atomicAdd(out + (idx0 + k * HW), t * fmaf(fr, t1 - t0, t0));
    }
}

extern "C" void kernel_launch(void* const* d_in, const int* in_sizes, int n_in,
                              void* d_out, int out_size, void* d_ws, size_t ws_size,
                              hipStream_t stream) {
    const float* ev = (const float*)d_in[0];
    const float* w1 = (const float*)d_in[4];
    const float* b1 = (const float*)d_in[5];
    const float* w2 = (const float*)d_in[6];
    const float* b2 = (const float*)d_in[7];
    const float* w3 = (const float*)d_in[8];
    const float* b3 = (const float*)d_in[9];
    float* out = (float*)d_out;
    int n = in_sizes[0] / 5;

    size_t off_table  = 0;                             // (2049)*4 -> pad 256
    size_t off_cursor = 8448;
    size_t off_bdata  = off_cursor + (size_t)NBUCKET * 4;
    size_t need       = off_bdata + (size_t)NBUCKET * CAP * 4;   // ~16.8 MB

    char* ws = (char*)d_ws;
    float* table = (float*)(ws + off_table);

    if (ws_size >= need) {
        unsigned* gCursor    = (unsigned*)(ws + off_cursor);
        unsigned* bucketData = (unsigned*)(ws + off_bdata);

        hipLaunchKernelGGL(zero_kernel, dim3((NBUCKET + 255) / 256), dim3(256),
                           0, stream, gCursor, NBUCKET);
        hipLaunchKernelGGL(build_table_kernel, dim3(TABLE_N + 1), dim3(128),
                           0, stream, w1, b1, w2, b2, w3, b3, table, TABLE_N);
        hipLaunchKernelGGL(place3_kernel, dim3((n + PB_EVENTS - 1) / PB_EVENTS),
                           dim3(PB_THREADS), 0, stream, ev, n, gCursor, bucketData);
        hipLaunchKernelGGL(gather7_kernel, dim3(NBUCKET), dim3(256), 0, stream,
                           gCursor, bucketData, table, out);
    } else {
        // known-good round-1 path
        int tn = TABLE_N;
        while (tn > 64 && (size_t)(tn + 1) * sizeof(float) > ws_size) tn >>= 1;
        hipLaunchKernelGGL(zero_out_kernel, dim3((out_size + 255) / 256), dim3(256),
                           0, stream, out, out_size);
        hipLaunchKernelGGL(build_table_kernel, dim3(tn + 1), dim3(128),
                           0, stream, w1, b1, w2, b2, w3, b3, table, tn);
        hipLaunchKernelGGL(scatter_kernel, dim3((n + 255) / 256), dim3(256), 0,
                           stream, ev, n, table, tn, out);
    }
}

// Round 2
// 155.274 us; speedup vs baseline: 1.3388x; 1.0051x over previous
//
#include <hip/hip_runtime.h>

// QuantizationLayer: lerp-table MLP + LDS-hist bucket sort + linked-list gather.
// R1: 18M scattered global atomics = 868 us (scattered-transaction ceiling ~21G/s).
// R4-R7: bucket sort + LDS-tile gather ~110-130us -> 18M LDS f32 atomic floor.
// R8: atomic-free gather (per-x linked lists, register bins, coalesced store). 207.9us.
// R9: build_table was top dispatch (65us: 9 blocks on 256 CUs + acc[100] spilled,
//   VGPR_Count=52). Rebuilt block-per-sample, lane-per-hidden-unit. 156.1us.
// R10 (this round): top-5 now all harness ws-poison fills (43us @ 80% HBM peak,
//   ~2/iter, fixed overhead). Controllable remainder = place3+gather7 ~60us.
//   Theory: (a) place3 phase-2 merge = 860K global atomics where all 245 blocks
//   sweep the SAME bucket window in lockstep -> cross-XCD same-address
//   serialization. Fix: per-block staggered sweep order. (b) phase-1 issues
//   10M scalar loads (5/event, stride 20B). Fix: 4-event groups = 5 float4
//   loads (16B-aligned since 4 events = 80B). (c) gather7: 336 columns on 256
//   threads -> 80 straggler threads walk 2 lists. Fix: 384 threads, float4
//   table stage. Predict 156 -> ~130 if (a) is real, ~148 otherwise.

#define HID 100

constexpr int Wd = 336;
constexpr int Hd = 256;
constexpr int Cd = 9;                  // C_BINS
constexpr int HW = Wd * Hd;            // 86016
constexpr int PLANE = HW * Cd;         // 774144
constexpr int BATCH = PLANE * 2;       // 1548288

constexpr int NBUCKET = 4096;          // ((b*2+p01)<<8) | y
constexpr int CAP = 1024;              // max events/bucket (mean 488, +24 sigma)
constexpr int PB_THREADS = 512;
constexpr int PB_PER_THREAD = 16;
constexpr int PB_EVENTS = PB_THREADS * PB_PER_THREAD;   // 8192 events/block
constexpr int TABLE_N = 2048;
constexpr int GT_THREADS = 384;        // gather7 block width (1 col/thread)

// ---- zero the 4096 bucket cursors (no hipMemsetAsync inside capture) --
__global__ void zero_kernel(unsigned* __restrict__ p, int n) {
    int i = blockIdx.x * blockDim.x + threadIdx.x;
    if (i < n) p[i] = 0u;
}

// ---- table build: block per sample, lane per hidden unit --------------
__global__ __launch_bounds__(128) void
build_table_kernel(const float* __restrict__ w1,
                   const float* __restrict__ b1,
                   const float* __restrict__ w2,
                   const float* __restrict__ b2,
                   const float* __restrict__ w3,
                   const float* __restrict__ b3,
                   float* __restrict__ table, int table_n) {
    __shared__ float h1[HID];
    __shared__ float partial[128];
    int i = blockIdx.x;                 // 0 .. table_n inclusive
    if (i > table_n) return;
    int tid = threadIdx.x;
    float s = -1.0f + 2.0f * (float)i / (float)table_n;

    if (tid < HID) {
        float h = fmaf(s, w1[tid], b1[tid]);
        h1[tid] = fmaxf(h, 0.1f * h);
    }
    __syncthreads();

    float o = 0.0f;
    if (tid < HID) {
        float a0 = b2[tid], a1 = 0.0f, a2 = 0.0f, a3 = 0.0f;
#pragma unroll
        for (int j = 0; j < HID; j += 4) {
            a0 = fmaf(h1[j + 0], w2[(j + 0) * HID + tid], a0);
            a1 = fmaf(h1[j + 1], w2[(j + 1) * HID + tid], a1);
            a2 = fmaf(h1[j + 2], w2[(j + 2) * HID + tid], a2);
            a3 = fmaf(h1[j + 3], w2[(j + 3) * HID + tid], a3);
        }
        float acc = (a0 + a1) + (a2 + a3);
        float h2 = fmaxf(acc, 0.1f * acc);
        o = h2 * w3[tid];
    }
    partial[tid] = o;
    __syncthreads();
#pragma unroll
    for (int s2 = 64; s2 > 0; s2 >>= 1) {
        if (tid < s2) partial[tid] += partial[tid + s2];
        __syncthreads();
    }
    if (tid == 0) table[i] = partial[0] + b3[0];
}

// ---- place3: LDS-hist bucket sort, single count pass ------------------
__global__ __launch_bounds__(PB_THREADS) void
place3_kernel(const float* __restrict__ ev, int n,
              unsigned* __restrict__ gCursor,
              unsigned* __restrict__ bucketData) {
    __shared__ unsigned cnt[NBUCKET];    // 16 KB
    __shared__ unsigned base[NBUCKET];   // 16 KB
    int tid = threadIdx.x;
    for (int c = tid; c < NBUCKET; c += PB_THREADS) cnt[c] = 0u;
    __syncthreads();

    int ev0 = blockIdx.x * PB_EVENTS;
    unsigned pk[PB_PER_THREAD];          // packed (x<<23)|t_q23
    unsigned meta[PB_PER_THREAD];        // (bucket<<13)|rank, or ~0 = invalid

    // phase 1: count via LDS atomic; the RETURN VALUE is the local rank.
    // 4 consecutive events per thread-group = 5 float4 loads (80B, 16B-aligned
    // since ev0 and the group index are multiples of 4) -> 4x fewer load instrs.
#pragma unroll
    for (int j = 0; j < PB_PER_THREAD / 4; ++j) {
        int i0 = ev0 + (j * PB_THREADS + tid) * 4;   // first event of group
        float fx[4], fy[4], ft[4], fp[4], fb[4];
        bool ok4 = (i0 + 3 < n);
        if (ok4) {
            const float4* q = (const float4*)(ev + (size_t)i0 * 5);
            float4 v0 = q[0], v1 = q[1], v2 = q[2], v3 = q[3], v4 = q[4];
            fx[0]=v0.x; fy[0]=v0.y; ft[0]=v0.z; fp[0]=v0.w; fb[0]=v1.x;
            fx[1]=v1.y; fy[1]=v1.z; ft[1]=v1.w; fp[1]=v2.x; fb[1]=v2.y;
            fx[2]=v2.z; fy[2]=v2.w; ft[2]=v3.x; fp[2]=v3.y; fb[2]=v3.z;
            fx[3]=v3.w; fy[3]=v4.x; ft[3]=v4.y; fp[3]=v4.z; fb[3]=v4.w;
        } else {
#pragma unroll
            for (int k = 0; k < 4; ++k) {
                int i = i0 + k;
                if (i < n) {
                    const float* e = ev + (size_t)i * 5;
                    fx[k]=e[0]; fy[k]=e[1]; ft[k]=e[2]; fp[k]=e[3]; fb[k]=e[4];
                } else {
                    fp[k] = 2.0e9f;   // sentinel -> marked invalid below
                }
            }
        }
#pragma unroll
        for (int k = 0; k < 4; ++k) {
            int slot = j * 4 + k;
            int i = i0 + k;
            if (i < n) {
                int p01 = fp[k] > 0.0f ? 1 : 0;
                unsigned bucket = (unsigned)(((p01 + 2 * (int)fb[k]) << 8) | (int)fy[k]);
                unsigned tq = (unsigned)(ft[k] * 8388608.0f);  // t in [0,1) -> 23b
                pk[slot] = ((unsigned)(int)fx[k] << 23) | tq;
                unsigned r = atomicAdd(&cnt[bucket], 1u);      // local rank
                meta[slot] = (bucket << 13) | r;               // r < 8192
            } else {
                meta[slot] = 0xFFFFFFFFu;
            }
        }
    }
    __syncthreads();

    // phase 2: merge per-block counts into global cursors -> base.
    // Staggered sweep: without the stagger all blocks update the SAME
    // 512-bucket window simultaneously -> cross-XCD same-address atomic
    // serialization. Block-dependent start kills same-address concurrency.
    unsigned off = ((unsigned)blockIdx.x * 67u) & (NBUCKET - 1);
    for (int c0 = tid; c0 < NBUCKET; c0 += PB_THREADS) {
        int c = (int)(((unsigned)c0 + off) & (NBUCKET - 1));
        unsigned k = cnt[c];
        base[c] = k ? atomicAdd(&gCursor[c], k) : 0u;
    }
    __syncthreads();

    // phase 3: pure stores to exact slots (no second count pass)
#pragma unroll
    for (int j = 0; j < PB_PER_THREAD; ++j) {
        unsigned m = meta[j];
        if (m != 0xFFFFFFFFu) {
            unsigned bucket = m >> 13;
            unsigned pos = base[bucket] + (m & 0x1FFFu);
            if (pos < CAP)   // statistically impossible overflow; guard OOB
                bucketData[(size_t)bucket * CAP + pos] = pk[j];
        }
    }
}

// ---- gather7: block per bucket, per-column linked lists, no atomic acc -
__global__ __launch_bounds__(GT_THREADS) void
gather7_kernel(const unsigned* __restrict__ gCursor,
               const unsigned* __restrict__ bucketData,
               const float* __restrict__ gtable,
               float* __restrict__ out) {
    __shared__ __align__(16) float table[TABLE_N + 4];  // 8.2 KB
    __shared__ int   head[Wd];             // 1.3 KB
    __shared__ int   nxt[CAP];             // 4 KB
    __shared__ unsigned evs[CAP];          // 4 KB   (total ~17.5 KB)
    int tid = threadIdx.x;
    int bucket = blockIdx.x;
    // table stage: 512 float4 + 1 tail (gtable is at ws offset 0 -> 16B aligned)
    const float4* gt4 = (const float4*)gtable;
    for (int i = tid; i < TABLE_N / 4; i += GT_THREADS)
        ((float4*)table)[i] = gt4[i];
    if (tid == 0) table[TABLE_N] = gtable[TABLE_N];
    for (int i = tid; i < Wd; i += GT_THREADS) head[i] = -1;
    __syncthreads();

    unsigned c = gCursor[bucket];
    if (c > CAP) c = CAP;
    const unsigned* __restrict__ data = bucketData + (size_t)bucket * CAP;

    // phase 1: stash events, build per-x linked lists (1 atomicExch/event)
    for (unsigned e = tid; e < c; e += GT_THREADS) {
        unsigned pkd = data[e];
        evs[e] = pkd;
        int x = (int)(pkd >> 23);
        nxt[e] = atomicExch(&head[x], (int)e);
    }
    __syncthreads();

    int y = bucket & 255;
    int bp = bucket >> 8;                 // p01 + 2*b
    int b = bp >> 1, p01 = bp & 1;
    size_t rowbase = (size_t)(b * (2 * Cd) + p01 * Cd) * (size_t)HW
                   + (size_t)y * (size_t)Wd;

    // phase 2: thread-per-column list walk (384 threads -> exactly 1 column
    // per thread, no 2-list stragglers), 9 register accumulators,
    // coalesced direct store (covers empty columns with zeros).
    int x = tid;
    if (x < Wd) {
        float acc[Cd];
#pragma unroll
        for (int k = 0; k < Cd; ++k) acc[k] = 0.0f;
        for (int e = head[x]; e != -1; e = nxt[e]) {
            unsigned pkd = evs[e];
            float t = (float)(pkd & 0x7FFFFFu) * (1.0f / 8388608.0f);
            float u0 = (t + 1.0f) * (0.5f * (float)TABLE_N);  // in [1024,2048)
            int ii0 = (int)u0;                                 // [1024,2047]
            float fr = u0 - (float)ii0;                        // shared by all k
#pragma unroll
            for (int k = 0; k < Cd; ++k) {
                int ii = ii0 - 128 * k;        // k/8 shift = exactly 128 cells
                float t0 = table[ii], t1 = table[ii + 1];
                acc[k] = fmaf(t, fmaf(fr, t1 - t0, t0), acc[k]);
            }
        }
#pragma unroll
        for (int k = 0; k < Cd; ++k)
            out[rowbase + (size_t)k * HW + x] = acc[k];
    }
}

// ---- round-1 fallback scatter (known-good; used if ws too small) ------
__global__ void zero_out_kernel(float* __restrict__ p, int n) {
    int i = blockIdx.x * blockDim.x + threadIdx.x;
    if (i < n) p[i] = 0.0f;
}

__global__ void scatter_kernel(const float* __restrict__ ev, int n,
                               const float* __restrict__ table, int table_n,
                               float* __restrict__ out) {
    int i = blockIdx.x * blockDim.x + threadIdx.x;
    if (i >= n) return;
    const float* e = ev + (size_t)i * 5;
    float t = e[2];
    int idx0 = (int)e[0] + Wd * (int)e[1] + (e[3] > 0.0f ? PLANE : 0) + BATCH * (int)e[4];
    float half_n = 0.5f * (float)table_n;
#pragma unroll
    for (int k = 0; k < Cd; ++k) {
        float u = (t - 0.125f * (float)k + 1.0f) * half_n;
        int ii = (int)u;
        ii = ii < 0 ? 0 : (ii > table_n - 1 ? table_n - 1 : ii);
        float fr = u - (float)ii;
        float t0 = table[ii], t1 = table[ii + 1];
        atomicAdd(out + (idx0 + k * HW), t * fmaf(fr, t1 - t0, t0));
    }
}

extern "C" void kernel_launch(void* const* d_in, const int* in_sizes, int n_in,
                              void* d_out, int out_size, void* d_ws, size_t ws_size,
                              hipStream_t stream) {
    const float* ev = (const float*)d_in[0];
    const float* w1 = (const float*)d_in[4];
    const float* b1 = (const float*)d_in[5];
    const float* w2 = (const float*)d_in[6];
    const float* b2 = (const float*)d_in[7];
    const float* w3 = (const float*)d_in[8];
    const float* b3 = (const float*)d_in[9];
    float* out = (float*)d_out;
    int n = in_sizes[0] / 5;

    size_t off_table  = 0;                             // (2049)*4 -> pad 256
    size_t off_cursor = 8448;
    size_t off_bdata  = off_cursor + (size_t)NBUCKET * 4;
    size_t need       = off_bdata + (size_t)NBUCKET * CAP * 4;   // ~16.8 MB

    char* ws = (char*)d_ws;
    float* table = (float*)(ws + off_table);

    if (ws_size >= need) {
        unsigned* gCursor    = (unsigned*)(ws + off_cursor);
        unsigned* bucketData = (unsigned*)(ws + off_bdata);

        hipLaunchKernelGGL(zero_kernel, dim3((NBUCKET + 255) / 256), dim3(256),
                           0, stream, gCursor, NBUCKET);
        hipLaunchKernelGGL(build_table_kernel, dim3(TABLE_N + 1), dim3(128),
                           0, stream, w1, b1, w2, b2, w3, b3, table, TABLE_N);
        hipLaunchKernelGGL(place3_kernel, dim3((n + PB_EVENTS - 1) / PB_EVENTS),
                           dim3(PB_THREADS), 0, stream, ev, n, gCursor, bucketData);
        hipLaunchKernelGGL(gather7_kernel, dim3(NBUCKET), dim3(GT_THREADS), 0, stream,
                           gCursor, bucketData, table, out);
    } else {
        // known-good round-1 path
        int tn = TABLE_N;
        while (tn > 64 && (size_t)(tn + 1) * sizeof(float) > ws_size) tn >>= 1;
        hipLaunchKernelGGL(zero_out_kernel, dim3((out_size + 255) / 256), dim3(256),
                           0, stream, out, out_size);
        hipLaunchKernelGGL(build_table_kernel, dim3(tn + 1), dim3(128),
                           0, stream, w1, b1, w2, b2, w3, b3, table, tn);
        hipLaunchKernelGGL(scatter_kernel, dim3((n + 255) / 256), dim3(256), 0,
                           stream, ev, n, table, tn, out);
    }
}

// Round 3
// 154.419 us; speedup vs baseline: 1.3462x; 1.0055x over previous
//
#include <hip/hip_runtime.h>

// QuantizationLayer: lerp-table MLP + LDS-hist bucket sort + linked-list gather.
// R1: 18M scattered global atomics = 868 us.
// R4-R7: bucket sort + LDS-tile gather ~110-130us -> 18M LDS f32 atomic floor.
// R8: atomic-free gather (per-x linked lists, register bins). 207.9us.
// R9: build_table rebuilt block-per-sample (was 65us: 9 blocks + spilled acc[100]).
//   156.1us.
// R10: place3 staggered-merge + float4 event loads + gather 384 threads: NEUTRAL
//   (155.3us) -> those theories wrong. Top-5 = harness 256MiB ws-poison fills
//   (~42us each @ 80% HBM peak, fixed). Our kernels each <41us; controllable
//   remainder ~30-70us total, place3/gather7 within 2-4x of streaming floors.
// R11 (this round): gather8 = 4 buckets/block: table staged ONCE (saves 3/4 of
//   33MB L2 re-stage), double-buffered {head,nxt,evs} so bucket g+1's coalesced
//   global loads retire UNDER bucket g's list walk (latency hiding; was fully
//   serial per block). zero_kernel folded into build_table (one fewer launch).
//   Predict 155 -> ~142. If neutral: window is fill-dominated -> ROOFLINE.

#define HID 100

constexpr int Wd = 336;
constexpr int Hd = 256;
constexpr int Cd = 9;                  // C_BINS
constexpr int HW = Wd * Hd;            // 86016
constexpr int PLANE = HW * Cd;         // 774144
constexpr int BATCH = PLANE * 2;       // 1548288

constexpr int NBUCKET = 4096;          // ((b*2+p01)<<8) | y
constexpr int CAP = 1024;              // max events/bucket (mean 488, +24 sigma)
constexpr int PB_THREADS = 512;
constexpr int PB_PER_THREAD = 16;
constexpr int PB_EVENTS = PB_THREADS * PB_PER_THREAD;   // 8192 events/block
constexpr int TABLE_N = 2048;
constexpr int GT_THREADS = 384;        // gather block width (1 col/thread)
constexpr int GB = 4;                  // buckets per gather block

// ---- table build: block per sample, lane per hidden unit --------------
// Also zeroes the 4096 bucket cursors (blocks 0..31), saving a launch.
__global__ __launch_bounds__(128) void
build_table_kernel(const float* __restrict__ w1,
                   const float* __restrict__ b1,
                   const float* __restrict__ w2,
                   const float* __restrict__ b2,
                   const float* __restrict__ w3,
                   const float* __restrict__ b3,
                   float* __restrict__ table, int table_n,
                   unsigned* __restrict__ gCursor) {
    __shared__ float h1[HID];
    __shared__ float partial[128];
    int i = blockIdx.x;                 // 0 .. table_n inclusive
    int tid = threadIdx.x;
    if (gCursor != nullptr && i < NBUCKET / 128)
        gCursor[i * 128 + tid] = 0u;
    if (i > table_n) return;
    float s = -1.0f + 2.0f * (float)i / (float)table_n;

    if (tid < HID) {
        float h = fmaf(s, w1[tid], b1[tid]);
        h1[tid] = fmaxf(h, 0.1f * h);
    }
    __syncthreads();

    float o = 0.0f;
    if (tid < HID) {
        float a0 = b2[tid], a1 = 0.0f, a2 = 0.0f, a3 = 0.0f;
#pragma unroll
        for (int j = 0; j < HID; j += 4) {
            a0 = fmaf(h1[j + 0], w2[(j + 0) * HID + tid], a0);
            a1 = fmaf(h1[j + 1], w2[(j + 1) * HID + tid], a1);
            a2 = fmaf(h1[j + 2], w2[(j + 2) * HID + tid], a2);
            a3 = fmaf(h1[j + 3], w2[(j + 3) * HID + tid], a3);
        }
        float acc = (a0 + a1) + (a2 + a3);
        float h2 = fmaxf(acc, 0.1f * acc);
        o = h2 * w3[tid];
    }
    partial[tid] = o;
    __syncthreads();
#pragma unroll
    for (int s2 = 64; s2 > 0; s2 >>= 1) {
        if (tid < s2) partial[tid] += partial[tid + s2];
        __syncthreads();
    }
    if (tid == 0) table[i] = partial[0] + b3[0];
}

// ---- place3: LDS-hist bucket sort, single count pass ------------------
__global__ __launch_bounds__(PB_THREADS) void
place3_kernel(const float* __restrict__ ev, int n,
              unsigned* __restrict__ gCursor,
              unsigned* __restrict__ bucketData) {
    __shared__ unsigned cnt[NBUCKET];    // 16 KB
    __shared__ unsigned base[NBUCKET];   // 16 KB
    int tid = threadIdx.x;
    for (int c = tid; c < NBUCKET; c += PB_THREADS) cnt[c] = 0u;
    __syncthreads();

    int ev0 = blockIdx.x * PB_EVENTS;
    unsigned pk[PB_PER_THREAD];          // packed (x<<23)|t_q23
    unsigned meta[PB_PER_THREAD];        // (bucket<<13)|rank, or ~0 = invalid

    // phase 1: count via LDS atomic; the RETURN VALUE is the local rank.
#pragma unroll
    for (int j = 0; j < PB_PER_THREAD / 4; ++j) {
        int i0 = ev0 + (j * PB_THREADS + tid) * 4;   // first event of group
        float fx[4], fy[4], ft[4], fp[4], fb[4];
        bool ok4 = (i0 + 3 < n);
        if (ok4) {
            const float4* q = (const float4*)(ev + (size_t)i0 * 5);
            float4 v0 = q[0], v1 = q[1], v2 = q[2], v3 = q[3], v4 = q[4];
            fx[0]=v0.x; fy[0]=v0.y; ft[0]=v0.z; fp[0]=v0.w; fb[0]=v1.x;
            fx[1]=v1.y; fy[1]=v1.z; ft[1]=v1.w; fp[1]=v2.x; fb[1]=v2.y;
            fx[2]=v2.z; fy[2]=v2.w; ft[2]=v3.x; fp[2]=v3.y; fb[2]=v3.z;
            fx[3]=v3.w; fy[3]=v4.x; ft[3]=v4.y; fp[3]=v4.z; fb[3]=v4.w;
        } else {
#pragma unroll
            for (int k = 0; k < 4; ++k) {
                int i = i0 + k;
                if (i < n) {
                    const float* e = ev + (size_t)i * 5;
                    fx[k]=e[0]; fy[k]=e[1]; ft[k]=e[2]; fp[k]=e[3]; fb[k]=e[4];
                } else {
                    fp[k] = 2.0e9f;
                }
            }
        }
#pragma unroll
        for (int k = 0; k < 4; ++k) {
            int slot = j * 4 + k;
            int i = i0 + k;
            if (i < n) {
                int p01 = fp[k] > 0.0f ? 1 : 0;
                unsigned bucket = (unsigned)(((p01 + 2 * (int)fb[k]) << 8) | (int)fy[k]);
                unsigned tq = (unsigned)(ft[k] * 8388608.0f);  // t in [0,1) -> 23b
                pk[slot] = ((unsigned)(int)fx[k] << 23) | tq;
                unsigned r = atomicAdd(&cnt[bucket], 1u);      // local rank
                meta[slot] = (bucket << 13) | r;               // r < 8192
            } else {
                meta[slot] = 0xFFFFFFFFu;
            }
        }
    }
    __syncthreads();

    // phase 2: merge per-block counts into global cursors -> base.
    unsigned off = ((unsigned)blockIdx.x * 67u) & (NBUCKET - 1);
    for (int c0 = tid; c0 < NBUCKET; c0 += PB_THREADS) {
        int c = (int)(((unsigned)c0 + off) & (NBUCKET - 1));
        unsigned k = cnt[c];
        base[c] = k ? atomicAdd(&gCursor[c], k) : 0u;
    }
    __syncthreads();

    // phase 3: pure stores to exact slots
#pragma unroll
    for (int j = 0; j < PB_PER_THREAD; ++j) {
        unsigned m = meta[j];
        if (m != 0xFFFFFFFFu) {
            unsigned bucket = m >> 13;
            unsigned pos = base[bucket] + (m & 0x1FFFu);
            if (pos < CAP)   // statistically impossible overflow; guard OOB
                bucketData[(size_t)bucket * CAP + pos] = pk[j];
        }
    }
}

// ---- gather8: 4 buckets/block, double-buffered fill||walk -------------
// Phase-block g: WALK(g-1) on buffer buf^1 runs while FILL(g)'s coalesced
// global loads (issued first) are in flight; then barrier; tiny head reset;
// barrier. Table staged once for all 4 buckets.
__global__ __launch_bounds__(GT_THREADS) void
gather8_kernel(const unsigned* __restrict__ gCursor,
               const unsigned* __restrict__ bucketData,
               const float* __restrict__ gtable,
               float* __restrict__ out) {
    __shared__ __align__(16) float table[TABLE_N + 4];  // 8.2 KB
    __shared__ int   head[2][Wd];          // 2.7 KB
    __shared__ int   nxt[2][CAP];          // 8 KB
    __shared__ unsigned evs[2][CAP];       // 8 KB   (total ~27 KB -> 5 blk/CU)
    __shared__ unsigned csh[GB];
    int tid = threadIdx.x;
    int b0 = blockIdx.x * GB;

    // stage table once (gtable at ws offset 0 -> 16B aligned)
    const float4* gt4 = (const float4*)gtable;
    for (int i = tid; i < TABLE_N / 4; i += GT_THREADS)
        ((float4*)table)[i] = gt4[i];
    if (tid == 0) table[TABLE_N] = gtable[TABLE_N];
    if (tid < GB) {
        unsigned c = gCursor[b0 + tid];
        csh[tid] = c > CAP ? CAP : c;
    }
    for (int i = tid; i < Wd; i += GT_THREADS) { head[0][i] = -1; head[1][i] = -1; }
    __syncthreads();

    for (int g = 0; g < GB; ++g) {
        int buf = g & 1;
        unsigned c = csh[g];
        const unsigned* __restrict__ data = bucketData + (size_t)(b0 + g) * CAP;

        // FILL(g) loads issued FIRST so they retire under WALK(g-1)
        unsigned e0 = tid, e1 = tid + GT_THREADS, e2 = tid + 2 * GT_THREADS;
        unsigned p0 = 0, p1 = 0, p2 = 0;
        if (e0 < c) p0 = data[e0];
        if (e1 < c) p1 = data[e1];
        if (e2 < c) p2 = data[e2];

        // WALK(g-1): thread-per-column list walk on the other buffer
        if (g > 0) {
            int pb = buf ^ 1;
            int bk = b0 + g - 1;
            int y = bk & 255;
            int bp = bk >> 8;                 // p01 + 2*b
            int b = bp >> 1, p01 = bp & 1;
            size_t rowbase = (size_t)(b * (2 * Cd) + p01 * Cd) * (size_t)HW
                           + (size_t)y * (size_t)Wd;
            int x = tid;
            if (x < Wd) {
                float acc[Cd];
#pragma unroll
                for (int k = 0; k < Cd; ++k) acc[k] = 0.0f;
                for (int e = head[pb][x]; e != -1; e = nxt[pb][e]) {
                    unsigned pkd = evs[pb][e];
                    float t = (float)(pkd & 0x7FFFFFu) * (1.0f / 8388608.0f);
                    float u0 = (t + 1.0f) * (0.5f * (float)TABLE_N); // [1024,2048)
                    int ii0 = (int)u0;
                    float fr = u0 - (float)ii0;
#pragma unroll
                    for (int k = 0; k < Cd; ++k) {
                        int ii = ii0 - 128 * k;    // k/8 shift = 128 cells
                        float t0 = table[ii], t1 = table[ii + 1];
                        acc[k] = fmaf(t, fmaf(fr, t1 - t0, t0), acc[k]);
                    }
                }
#pragma unroll
                for (int k = 0; k < Cd; ++k)
                    out[rowbase + (size_t)k * HW + x] = acc[k];
            }
        }

        // FILL(g) commit: stash + linked-list build (1 atomicExch/event)
        if (e0 < c) { evs[buf][e0] = p0; nxt[buf][e0] = atomicExch(&head[buf][p0 >> 23], (int)e0); }
        if (e1 < c) { evs[buf][e1] = p1; nxt[buf][e1] = atomicExch(&head[buf][p1 >> 23], (int)e1); }
        if (e2 < c) { evs[buf][e2] = p2; nxt[buf][e2] = atomicExch(&head[buf][p2 >> 23], (int)e2); }
        __syncthreads();

        // reset the buffer WALK(g-1) just finished; FILL(g+1) will use it
        if (g + 1 < GB)
            for (int i = tid; i < Wd; i += GT_THREADS) head[buf ^ 1][i] = -1;
        __syncthreads();
    }

    // final walk: bucket GB-1
    {
        int pb = (GB - 1) & 1;
        int bk = b0 + GB - 1;
        int y = bk & 255;
        int bp = bk >> 8;
        int b = bp >> 1, p01 = bp & 1;
        size_t rowbase = (size_t)(b * (2 * Cd) + p01 * Cd) * (size_t)HW
                       + (size_t)y * (size_t)Wd;
        int x = tid;
        if (x < Wd) {
            float acc[Cd];
#pragma unroll
            for (int k = 0; k < Cd; ++k) acc[k] = 0.0f;
            for (int e = head[pb][x]; e != -1; e = nxt[pb][e]) {
                unsigned pkd = evs[pb][e];
                float t = (float)(pkd & 0x7FFFFFu) * (1.0f / 8388608.0f);
                float u0 = (t + 1.0f) * (0.5f * (float)TABLE_N);
                int ii0 = (int)u0;
                float fr = u0 - (float)ii0;
#pragma unroll
                for (int k = 0; k < Cd; ++k) {
                    int ii = ii0 - 128 * k;
                    float t0 = table[ii], t1 = table[ii + 1];
                    acc[k] = fmaf(t, fmaf(fr, t1 - t0, t0), acc[k]);
                }
            }
#pragma unroll
            for (int k = 0; k < Cd; ++k)
                out[rowbase + (size_t)k * HW + x] = acc[k];
        }
    }
}

// ---- round-1 fallback scatter (known-good; used if ws too small) ------
__global__ void zero_out_kernel(float* __restrict__ p, int n) {
    int i = blockIdx.x * blockDim.x + threadIdx.x;
    if (i < n) p[i] = 0.0f;
}

__global__ void scatter_kernel(const float* __restrict__ ev, int n,
                               const float* __restrict__ table, int table_n,
                               float* __restrict__ out) {
    int i = blockIdx.x * blockDim.x + threadIdx.x;
    if (i >= n) return;
    const float* e = ev + (size_t)i * 5;
    float t = e[2];
    int idx0 = (int)e[0] + Wd * (int)e[1] + (e[3] > 0.0f ? PLANE : 0) + BATCH * (int)e[4];
    float half_n = 0.5f * (float)table_n;
#pragma unroll
    for (int k = 0; k < Cd; ++k) {
        float u = (t - 0.125f * (float)k + 1.0f) * half_n;
        int ii = (int)u;
        ii = ii < 0 ? 0 : (ii > table_n - 1 ? table_n - 1 : ii);
        float fr = u - (float)ii;
        float t0 = table[ii], t1 = table[ii + 1];
        atomicAdd(out + (idx0 + k * HW), t * fmaf(fr, t1 - t0, t0));
    }
}

extern "C" void kernel_launch(void* const* d_in, const int* in_sizes, int n_in,
                              void* d_out, int out_size, void* d_ws, size_t ws_size,
                              hipStream_t stream) {
    const float* ev = (const float*)d_in[0];
    const float* w1 = (const float*)d_in[4];
    const float* b1 = (const float*)d_in[5];
    const float* w2 = (const float*)d_in[6];
    const float* b2 = (const float*)d_in[7];
    const float* w3 = (const float*)d_in[8];
    const float* b3 = (const float*)d_in[9];
    float* out = (float*)d_out;
    int n = in_sizes[0] / 5;

    size_t off_table  = 0;                             // (2049)*4 -> pad 256
    size_t off_cursor = 8448;
    size_t off_bdata  = off_cursor + (size_t)NBUCKET * 4;
    size_t need       = off_bdata + (size_t)NBUCKET * CAP * 4;   // ~16.8 MB

    char* ws = (char*)d_ws;
    float* table = (float*)(ws + off_table);

    if (ws_size >= need) {
        unsigned* gCursor    = (unsigned*)(ws + off_cursor);
        unsigned* bucketData = (unsigned*)(ws + off_bdata);

        hipLaunchKernelGGL(build_table_kernel, dim3(TABLE_N + 1), dim3(128),
                           0, stream, w1, b1, w2, b2, w3, b3, table, TABLE_N,
                           gCursor);
        hipLaunchKernelGGL(place3_kernel, dim3((n + PB_EVENTS - 1) / PB_EVENTS),
                           dim3(PB_THREADS), 0, stream, ev, n, gCursor, bucketData);
        hipLaunchKernelGGL(gather8_kernel, dim3(NBUCKET / GB), dim3(GT_THREADS),
                           0, stream, gCursor, bucketData, table, out);
    } else {
        // known-good round-1 path
        int tn = TABLE_N;
        while (tn > 64 && (size_t)(tn + 1) * sizeof(float) > ws_size) tn >>= 1;
        hipLaunchKernelGGL(zero_out_kernel, dim3((out_size + 255) / 256), dim3(256),
                           0, stream, out, out_size);
        hipLaunchKernelGGL(build_table_kernel, dim3(tn + 1), dim3(128),
                           0, stream, w1, b1, w2, b2, w3, b3, table, tn,
                           (unsigned*)nullptr);
        hipLaunchKernelGGL(scatter_kernel, dim3((n + 255) / 256), dim3(256), 0,
                           stream, ev, n, table, tn, out);
    }
}